// Round 1
// baseline (2077.923 us; speedup 1.0000x reference)
//
#include <hip/hip_runtime.h>
#include <math.h>

#define NN 100000
#define NE 1600000
#define KF 48

// ---------------- scatter-add: 12 threads per edge, float4 per thread ---------------
__global__ __launch_bounds__(256) void scatter2_kernel(
    const float* __restrict__ x,
    const int* __restrict__ ei_pos,
    const int* __restrict__ ei_neg,
    float* acc_pos,
    float* acc_neg)
{
    const int  list = blockIdx.y;
    const int*  ei  = list ? ei_neg  : ei_pos;
    float*      acc = list ? acc_neg : acc_pos;

    long t = (long)blockIdx.x * blockDim.x + threadIdx.x;
    const long total = (long)NE * 12;
    if (t >= total) return;

    int e  = (int)(t / 12);
    int r  = (int)(t - (long)e * 12);
    int k4 = r * 4;

    int src = ei[e];          // row 0 of [2, E]
    int dst = ei[NE + e];     // row 1 of [2, E]

    const float4 v = *(const float4*)(x + (long)src * KF + k4);
    float* p = acc + (long)dst * KF + k4;

    unsafeAtomicAdd(p + 0, v.x);
    unsafeAtomicAdd(p + 1, v.y);
    unsafeAtomicAdd(p + 2, v.z);
    unsafeAtomicAdd(p + 3, v.w);
}

// ---------------- fused MLP (tanh) + linear + softmax: 1 thread per node -----------
// NOTE: xpos aliases out (x_pos accumulator lives in d_out). Each thread reads its
// own row fully before writing it, and no thread touches another node's row, so
// this is race-free. Do NOT mark xpos/out restrict.
__global__ __launch_bounds__(256) void mlp_softmax_kernel(
    const float* __restrict__ x,
    const float* xpos,
    const float* __restrict__ xneg,
    const float* __restrict__ W1,   // [144,16] row-major
    const float* __restrict__ b1,   // [16]
    const float* __restrict__ W2,   // [16,48] row-major
    const float* __restrict__ b2,   // [48]
    float* out)
{
    __shared__ float sW1[144 * 16];
    __shared__ float sW2[16 * 48];
    __shared__ float sb1[16];
    __shared__ float sb2[48];

    for (int i = threadIdx.x; i < 144 * 16; i += blockDim.x) sW1[i] = W1[i];
    for (int i = threadIdx.x; i < 16 * 48;  i += blockDim.x) sW2[i] = W2[i];
    if (threadIdx.x < 16) sb1[threadIdx.x] = b1[threadIdx.x];
    if (threadIdx.x < 48) sb2[threadIdx.x] = b2[threadIdx.x];
    __syncthreads();

    const int n = blockIdx.x * blockDim.x + threadIdx.x;
    if (n >= NN) return;

    // ---- h = tanh(cat(x, xpos, xneg) @ W1 + b1) ----
    float h[16];
#pragma unroll
    for (int j = 0; j < 16; ++j) h[j] = sb1[j];

    const float* srcs[3];
    srcs[0] = x    + (long)n * KF;
    srcs[1] = xpos + (long)n * KF;
    srcs[2] = xneg + (long)n * KF;

    for (int s = 0; s < 3; ++s) {
        const float* px = srcs[s];
        for (int i = 0; i < KF; ++i) {
            const float v = px[i];
            const float* w = &sW1[(s * KF + i) * 16];   // uniform addr -> LDS broadcast
#pragma unroll
            for (int j = 0; j < 16; ++j) h[j] += v * w[j];
        }
    }
#pragma unroll
    for (int j = 0; j < 16; ++j) h[j] = tanhf(h[j]);

    // ---- C = h @ W2 + b2 ----
    float C[KF];
#pragma unroll
    for (int k = 0; k < KF; ++k) C[k] = sb2[k];
    for (int j = 0; j < 16; ++j) {
        const float hv = h[j];
        const float* w = &sW2[j * KF];                  // uniform addr -> LDS broadcast
#pragma unroll
        for (int k = 0; k < KF; ++k) C[k] += hv * w[k];
    }

    // ---- softmax over 48 ----
    float m = C[0];
#pragma unroll
    for (int k = 1; k < KF; ++k) m = fmaxf(m, C[k]);
    float ssum = 0.f;
#pragma unroll
    for (int k = 0; k < KF; ++k) { C[k] = expf(C[k] - m); ssum += C[k]; }
    const float inv = 1.0f / ssum;

    float* po = out + (long)n * KF;
#pragma unroll
    for (int k = 0; k < KF; ++k) po[k] = C[k] * inv;
}

extern "C" void kernel_launch(void* const* d_in, const int* in_sizes, int n_in,
                              void* d_out, int out_size, void* d_ws, size_t ws_size,
                              hipStream_t stream)
{
    const float* x      = (const float*)d_in[0];
    const int*   ei_pos = (const int*)  d_in[1];
    const int*   ei_neg = (const int*)  d_in[2];
    const float* W1     = (const float*)d_in[3];
    const float* b1     = (const float*)d_in[4];
    const float* W2     = (const float*)d_in[5];
    const float* b2     = (const float*)d_in[6];

    float* out  = (float*)d_out;
    float* xpos = (float*)d_out;            // x_pos accumulator aliases the output
    float* xneg = (float*)d_ws;             // x_neg accumulator in workspace

    const size_t acc_bytes = (size_t)NN * KF * sizeof(float);

    // zero both accumulators (harness poisons d_out / d_ws with 0xAA)
    hipMemsetAsync(xpos, 0, acc_bytes, stream);
    hipMemsetAsync(xneg, 0, acc_bytes, stream);

    // scatter-add both edge lists in one launch (y = 0 pos, y = 1 neg)
    {
        const long total = (long)NE * 12;
        dim3 grid((unsigned)((total + 255) / 256), 2, 1);
        scatter2_kernel<<<grid, 256, 0, stream>>>(x, ei_pos, ei_neg, xpos, xneg);
    }

    // fused MLP + softmax
    {
        dim3 grid((NN + 255) / 256, 1, 1);
        mlp_softmax_kernel<<<grid, 256, 0, stream>>>(x, xpos, xneg, W1, b1, W2, b2, out);
    }
}

// Round 2
// 717.163 us; speedup vs baseline: 2.8974x; 2.8974x over previous
//
#include <hip/hip_runtime.h>
#include <math.h>

#define NN 100000
#define NE 1600000
#define KF 48
#define NSEG (2 * NN)          // pos segments then neg segments
#define NEDGE_ALL (2 * NE)

// ============================ CSR-build kernels ============================

// histogram of destinations for both lists
__global__ __launch_bounds__(256) void hist_kernel(
    const int* __restrict__ ei_pos,
    const int* __restrict__ ei_neg,
    int* __restrict__ deg)
{
    int e = blockIdx.x * blockDim.x + threadIdx.x;
    if (e >= NEDGE_ALL) return;
    int list = e >= NE;
    int ee = list ? e - NE : e;
    const int* ei = list ? ei_neg : ei_pos;
    int dst = ei[NE + ee];
    atomicAdd(&deg[list * NN + dst], 1);
}

// 3-kernel exclusive scan over deg[NSEG] -> offs[NSEG]
__global__ __launch_bounds__(256) void scan_block_kernel(
    const int* __restrict__ deg, int* __restrict__ offs, int* __restrict__ partial)
{
    __shared__ int lds[256];
    const int base = blockIdx.x * 1024;
    const int t = threadIdx.x;
    int v[4];
    int s = 0;
#pragma unroll
    for (int j = 0; j < 4; ++j) {
        int i = base + t * 4 + j;
        v[j] = (i < NSEG) ? deg[i] : 0;
        s += v[j];
    }
    lds[t] = s;
    __syncthreads();
    for (int d = 1; d < 256; d <<= 1) {
        int val = (t >= d) ? lds[t - d] : 0;
        __syncthreads();
        lds[t] += val;
        __syncthreads();
    }
    int run = lds[t] - s;          // exclusive prefix of this thread's chunk
    if (t == 255) partial[blockIdx.x] = lds[255];
#pragma unroll
    for (int j = 0; j < 4; ++j) {
        int i = base + t * 4 + j;
        if (i < NSEG) offs[i] = run;
        run += v[j];
    }
}

__global__ __launch_bounds__(256) void scan_partial_kernel(int* partial, int nb)
{
    __shared__ int lds[256];
    int t = threadIdx.x;
    int v = (t < nb) ? partial[t] : 0;
    lds[t] = v;
    __syncthreads();
    for (int d = 1; d < 256; d <<= 1) {
        int val = (t >= d) ? lds[t - d] : 0;
        __syncthreads();
        lds[t] += val;
        __syncthreads();
    }
    if (t < nb) partial[t] = lds[t] - v;   // exclusive
}

__global__ __launch_bounds__(256) void scan_add_kernel(
    int* __restrict__ offs, const int* __restrict__ partial)
{
    int i = blockIdx.x * blockDim.x + threadIdx.x;
    if (i < NSEG) offs[i] += partial[i >> 10];
}

// binning: uses offs itself as the cursor; after this kernel offs[seg] = end(seg)
__global__ __launch_bounds__(256) void bin_kernel(
    const int* __restrict__ ei_pos,
    const int* __restrict__ ei_neg,
    int* __restrict__ offs,
    int* __restrict__ srclist)
{
    int e = blockIdx.x * blockDim.x + threadIdx.x;
    if (e >= NEDGE_ALL) return;
    int list = e >= NE;
    int ee = list ? e - NE : e;
    const int* ei = list ? ei_neg : ei_pos;
    int src = ei[ee];
    int dst = ei[NE + ee];
    int slot = atomicAdd(&offs[list * NN + dst], 1);
    srclist[slot] = src;
}

// gather: one wave per (node, list). lanes 0..47 = feature columns.
// start(seg) = (seg==0 ? 0 : offs[seg-1]) since offs holds segment ends post-bin.
__global__ __launch_bounds__(256) void gather_kernel(
    const float* __restrict__ x,
    const int* __restrict__ srclist,
    const int* __restrict__ offs,
    float* __restrict__ xpos,
    float* __restrict__ xneg)
{
    int gw = (blockIdx.x * blockDim.x + threadIdx.x) >> 6;
    int lane = threadIdx.x & 63;
    if (gw >= NSEG) return;
    int list = gw >= NN;
    int n = list ? gw - NN : gw;
    int start = (gw == 0) ? 0 : offs[gw - 1];
    int end = offs[gw];

    float acc = 0.f;
    for (int kb = start; kb < end; kb += 64) {
        int idx = kb + lane;
        int my = (idx < end) ? srclist[idx] : 0;
        int cnt = min(64, end - kb);
        for (int j = 0; j < cnt; ++j) {
            int src = __shfl(my, j);
            if (lane < KF) acc += x[src * KF + lane];
        }
    }
    float* o = list ? xneg : xpos;
    if (lane < KF) o[n * KF + lane] = acc;
}

// ============== fallback scatter (round-1 path, if ws too small) ==============
__global__ __launch_bounds__(256) void scatter2_kernel(
    const float* __restrict__ x,
    const int* __restrict__ ei_pos,
    const int* __restrict__ ei_neg,
    float* acc_pos,
    float* acc_neg)
{
    const int list = blockIdx.y;
    const int* ei = list ? ei_neg : ei_pos;
    float* acc = list ? acc_neg : acc_pos;

    long t = (long)blockIdx.x * blockDim.x + threadIdx.x;
    const long total = (long)NE * 12;
    if (t >= total) return;

    int e = (int)(t / 12);
    int r = (int)(t - (long)e * 12);
    int k4 = r * 4;

    int src = ei[e];
    int dst = ei[NE + e];

    const float4 v = *(const float4*)(x + (long)src * KF + k4);
    float* p = acc + (long)dst * KF + k4;

    unsafeAtomicAdd(p + 0, v.x);
    unsafeAtomicAdd(p + 1, v.y);
    unsafeAtomicAdd(p + 2, v.z);
    unsafeAtomicAdd(p + 3, v.w);
}

// ---------------- fused MLP (tanh) + linear + softmax: 1 thread per node -----------
// NOTE: xpos aliases out. Each thread reads its own row fully before writing it.
__global__ __launch_bounds__(256) void mlp_softmax_kernel(
    const float* __restrict__ x,
    const float* xpos,
    const float* __restrict__ xneg,
    const float* __restrict__ W1,   // [144,16]
    const float* __restrict__ b1,
    const float* __restrict__ W2,   // [16,48]
    const float* __restrict__ b2,
    float* out)
{
    __shared__ float sW1[144 * 16];
    __shared__ float sW2[16 * 48];
    __shared__ float sb1[16];
    __shared__ float sb2[48];

    for (int i = threadIdx.x; i < 144 * 16; i += blockDim.x) sW1[i] = W1[i];
    for (int i = threadIdx.x; i < 16 * 48;  i += blockDim.x) sW2[i] = W2[i];
    if (threadIdx.x < 16) sb1[threadIdx.x] = b1[threadIdx.x];
    if (threadIdx.x < 48) sb2[threadIdx.x] = b2[threadIdx.x];
    __syncthreads();

    const int n = blockIdx.x * blockDim.x + threadIdx.x;
    if (n >= NN) return;

    float h[16];
#pragma unroll
    for (int j = 0; j < 16; ++j) h[j] = sb1[j];

    const float* srcs[3];
    srcs[0] = x    + (long)n * KF;
    srcs[1] = xpos + (long)n * KF;
    srcs[2] = xneg + (long)n * KF;

    for (int s = 0; s < 3; ++s) {
        const float* px = srcs[s];
        for (int i = 0; i < KF; ++i) {
            const float v = px[i];
            const float* w = &sW1[(s * KF + i) * 16];
#pragma unroll
            for (int j = 0; j < 16; ++j) h[j] += v * w[j];
        }
    }
#pragma unroll
    for (int j = 0; j < 16; ++j) h[j] = tanhf(h[j]);

    float C[KF];
#pragma unroll
    for (int k = 0; k < KF; ++k) C[k] = sb2[k];
    for (int j = 0; j < 16; ++j) {
        const float hv = h[j];
        const float* w = &sW2[j * KF];
#pragma unroll
        for (int k = 0; k < KF; ++k) C[k] += hv * w[k];
    }

    float m = C[0];
#pragma unroll
    for (int k = 1; k < KF; ++k) m = fmaxf(m, C[k]);
    float ssum = 0.f;
#pragma unroll
    for (int k = 0; k < KF; ++k) { C[k] = expf(C[k] - m); ssum += C[k]; }
    const float inv = 1.0f / ssum;

    float* po = out + (long)n * KF;
#pragma unroll
    for (int k = 0; k < KF; ++k) po[k] = C[k] * inv;
}

extern "C" void kernel_launch(void* const* d_in, const int* in_sizes, int n_in,
                              void* d_out, int out_size, void* d_ws, size_t ws_size,
                              hipStream_t stream)
{
    const float* x      = (const float*)d_in[0];
    const int*   ei_pos = (const int*)  d_in[1];
    const int*   ei_neg = (const int*)  d_in[2];
    const float* W1     = (const float*)d_in[3];
    const float* b1     = (const float*)d_in[4];
    const float* W2     = (const float*)d_in[5];
    const float* b2     = (const float*)d_in[6];

    float* out  = (float*)d_out;
    float* xpos = (float*)d_out;                 // x_pos accumulator aliases out

    const size_t acc_bytes     = (size_t)NN * KF * sizeof(float);      // 19.2 MB
    const size_t srclist_bytes = (size_t)NEDGE_ALL * sizeof(int);      // 12.8 MB
    const size_t deg_bytes     = (size_t)NSEG * sizeof(int);           // 800 KB
    const int    NB            = (NSEG + 1023) / 1024;                 // scan blocks

    // ws layout: [xneg | srclist | deg | offs | partial]
    size_t off = 0;
    char* ws = (char*)d_ws;
    float* xneg   = (float*)(ws + off); off += acc_bytes;
    int* srclist  = (int*)(ws + off);   off += srclist_bytes;
    int* deg      = (int*)(ws + off);   off += deg_bytes;
    int* offs     = (int*)(ws + off);   off += deg_bytes;
    int* partial  = (int*)(ws + off);   off += ((size_t)NB + 64) * sizeof(int);
    const size_t needed = off;

    if (ws_size >= needed) {
        // ---------------- CSR gather path ----------------
        hipMemsetAsync(deg, 0, deg_bytes, stream);

        hist_kernel<<<(NEDGE_ALL + 255) / 256, 256, 0, stream>>>(ei_pos, ei_neg, deg);

        scan_block_kernel<<<NB, 256, 0, stream>>>(deg, offs, partial);
        scan_partial_kernel<<<1, 256, 0, stream>>>(partial, NB);
        scan_add_kernel<<<(NSEG + 255) / 256, 256, 0, stream>>>(offs, partial);

        bin_kernel<<<(NEDGE_ALL + 255) / 256, 256, 0, stream>>>(ei_pos, ei_neg, offs, srclist);

        gather_kernel<<<(NSEG * 64 + 255) / 256, 256, 0, stream>>>(x, srclist, offs, xpos, xneg);
    } else {
        // ---------------- fallback: atomic scatter ----------------
        hipMemsetAsync(xpos, 0, acc_bytes, stream);
        hipMemsetAsync(xneg, 0, acc_bytes, stream);
        const long total = (long)NE * 12;
        dim3 grid((unsigned)((total + 255) / 256), 2, 1);
        scatter2_kernel<<<grid, 256, 0, stream>>>(x, ei_pos, ei_neg, xpos, xneg);
    }

    mlp_softmax_kernel<<<(NN + 255) / 256, 256, 0, stream>>>(x, xpos, xneg, W1, b1, W2, b2, out);
}